// Round 10
// baseline (144.925 us; speedup 1.0000x reference)
//
#include <hip/hip_runtime.h>
#include <stdint.h>

#define B 1024
#define F 256
#define D 64

typedef __attribute__((ext_vector_type(8))) short short8;
typedef __attribute__((ext_vector_type(4))) float f32x4;

__device__ __forceinline__ short f2bf(float f) {
    unsigned u = __builtin_bit_cast(unsigned, f);
    u += 0x7fff + ((u >> 16) & 1);   // RNE
    return (short)(u >> 16);
}
__device__ __forceinline__ float bf2f(short s) {
    unsigned u = ((unsigned)(unsigned short)s) << 16;
    return __builtin_bit_cast(float, u);
}
// pack two f32 -> two bf16 (round-half-up), 3 VALU
__device__ __forceinline__ unsigned pk_bf16(float a, float b) {
    unsigned ua = __builtin_bit_cast(unsigned, a) + 0x8000u;
    unsigned ub = __builtin_bit_cast(unsigned, b) + 0x8000u;
    return __builtin_amdgcn_perm(ub, ua, 0x07060302u);  // [bf16(a) | bf16(b)<<16]
}

__device__ __forceinline__ float dot4(float4 a, float4 b) {
    return a.x * b.x + a.y * b.y + a.z * b.z + a.w * b.w;
}

// ---------------------------------------------------------------------------
// Workspace layout:
//   trans : 2*F*D f32
//   qkv   : 3*F*D f32
//   At    : [F/32][F][32] bf16   (gate*cross, K-tiled)      = 128 KB
//   q2K   : [F/32][64][32] bf16  (qkv2^T, K-tiled, d-PERMUTED: physical slot
//                                 p=(d&3)*16+(d>>2) so fragment nt at lane l16
//                                 holds logical col l16*4+nt -> float4 stores)
// s is NOT materialized to global anymore: fused_sg computes it into LDS.
// ---------------------------------------------------------------------------

// Kernel A: trans/qkv = indicator @ W
__global__ void precompute_trans(const float* __restrict__ indicator,
                                 const float* __restrict__ W_qk,
                                 const float* __restrict__ W_qkv,
                                 float* __restrict__ trans,
                                 float* __restrict__ qkv) {
    int idx = blockIdx.x * blockDim.x + threadIdx.x;   // 0 .. 5*F*D
    int n   = idx / (F * D);
    int rem = idx - n * (F * D);
    int f   = rem / D;
    int e   = rem - f * D;
    const float* W = (n < 2) ? (W_qk + n * D * D) : (W_qkv + (n - 2) * D * D);
    const float* ind = indicator + f * D;
    float acc = 0.f;
#pragma unroll 8
    for (int d = 0; d < D; ++d) acc += ind[d] * W[d * D + e];
    if (n < 2) trans[n * F * D + f * D + e] = acc;
    else       qkv[(n - 2) * F * D + f * D + e] = acc;
}

// Kernel B (round-5 proven): At[(j>>5)][i][j&31] = gate(i,j) ? qkv1[i].qkv0[j] : 0
//   q2K[(i>>5)][p(j)][i&31] = qkv2[i][j], p(j)=(j&3)*16+(j>>2)
__global__ __launch_bounds__(256) void compute_Mt(const float* __restrict__ trans,
                                                  const float* __restrict__ qkv,
                                                  short* __restrict__ At,
                                                  short* __restrict__ q2K) {
    int j = blockIdx.x;    // F columns
    int i = threadIdx.x;   // F threads
    const float4* t0 = (const float4*)(trans + i * D);
    const float4* t1 = (const float4*)(trans + F * D + j * D);
    const float4* q1 = (const float4*)(qkv + F * D + i * D);
    const float4* q0 = (const float4*)(qkv + j * D);
    float d0 = 0.f, d1 = 0.f;
#pragma unroll
    for (int k = 0; k < D / 4; ++k) {
        float4 a = t0[k], b = t1[k], c = q1[k], e = q0[k];
        d0 += dot4(a, b);
        d1 += dot4(c, e);
    }
    float v = (d0 > 0.f) ? d1 : 0.f;
    At[((j >> 5) * F + i) * 32 + (j & 31)] = f2bf(v);
    if (j < D) {
        int p = (j & 3) * 16 + (j >> 2);   // d-permutation for float4 stores
        q2K[((i >> 5) * D + p) * 32 + (i & 31)] = f2bf(qkv[2 * F * D + i * D + j]);
    }
}

// FUSED kernel: one block = 2 batches, 512 threads / 8 waves, 2 blocks/CU.
// Phase 1: s[n,f] for both batches -> gL (f32), s1L (bf16) in LDS.
//          (no global round-trip for s; s-read phase of some blocks overlaps
//           gemm/write phase of others on the same CU — the round-0..9 split
//           kernels serialized these two memory phases chip-wide.)
// Phase 2: wave w -> batch (w&1), i-tile (w>>1)*64. acc[4][4].
//          A-fragments read DIRECTLY from At in L2 (wave-coalesced 1KB lines,
//          32 KB/wave; 128 MB aggregate ~= 4-5us of L2, latency hidden by
//          16 waves/CU). q2K (32 KB) staged once in LDS.
__global__ __launch_bounds__(512, 4) void fused_sg(const float* __restrict__ feature,
                                                   const float* __restrict__ qkv,
                                                   const short* __restrict__ At,
                                                   const short* __restrict__ q2K,
                                                   float* __restrict__ out) {
    int bp  = blockIdx.x;
    int b0  = bp * 2;
    int tid = threadIdx.x;

    __shared__ __align__(16) short q2L[8 * 64 * 32];   // 32 KB
    __shared__ __align__(16) short s1L[2 * F];         // 1 KB
    __shared__ __align__(16) float gL[2 * F];          // 2 KB

    // ---- phase 0: stage q2K into LDS ----
    {
        const float4* Qg = (const float4*)q2K;
        float4* Ql = (float4*)q2L;
#pragma unroll
        for (int v = tid; v < 2048; v += 512) Ql[v] = Qg[v];
    }

    // ---- phase 1: s for 2 batches; 16 lanes/row, 32 rows in flight ----
    {
        int rg = tid >> 4;    // 0..31
        int l  = tid & 15;
#pragma unroll 2
        for (int p = 0; p < 8; ++p) {
            int f = p * 32 + rg;
            float4 fv0 = ((const float4*)(feature + ((size_t)(b0 * F + f)) * D))[l];
            float4 fv1 = ((const float4*)(feature + ((size_t)((b0 + 1) * F + f)) * D))[l];
            float4 q0 = ((const float4*)(qkv + f * D))[l];
            float4 q1 = ((const float4*)(qkv + F * D + f * D))[l];
            float4 q2 = ((const float4*)(qkv + 2 * F * D + f * D))[l];
            float a00 = dot4(fv0, q0);
            float a01 = dot4(fv0, q1);
            float a02 = dot4(fv0, q2);
            float a10 = dot4(fv1, q0);
            float a11 = dot4(fv1, q1);
            float a12 = dot4(fv1, q2);
#pragma unroll
            for (int m = 1; m < 16; m <<= 1) {
                a00 += __shfl_xor(a00, m, 64);
                a01 += __shfl_xor(a01, m, 64);
                a02 += __shfl_xor(a02, m, 64);
                a10 += __shfl_xor(a10, m, 64);
                a11 += __shfl_xor(a11, m, 64);
                a12 += __shfl_xor(a12, m, 64);
            }
            if (l == 0) {
                gL[f]      = a00 * a02;
                gL[F + f]  = a10 * a12;
                s1L[f]     = f2bf(a01);
                s1L[F + f] = f2bf(a11);
            }
        }
    }
    __syncthreads();

    // ---- phase 2: MFMA GEMM, A from global (L2), B from LDS ----
    int w    = tid >> 6;
    int lane = tid & 63;
    int l16  = lane & 15;
    int lq   = lane >> 4;
    int kq   = lq * 8;
    int wc   = w & 1;        // batch within pair
    int it   = w >> 1;       // i-tile: rows [it*64, it*64+64)
    int b    = b0 + wc;

    f32x4 acc[4][4];
#pragma unroll
    for (int mt = 0; mt < 4; ++mt)
#pragma unroll
        for (int nt = 0; nt < 4; ++nt) acc[mt][nt] = (f32x4){0.f, 0.f, 0.f, 0.f};

    for (int jt = 0; jt < F / 32; ++jt) {
        // s1 fragment from LDS (broadcast within 16-lane groups)
        short8 sv = *(const short8*)(s1L + wc * F + jt * 32 + kq);
        float sf[8];
#pragma unroll
        for (int e = 0; e < 8; ++e) sf[e] = bf2f(sv[e]);

        // B fragments from LDS: q2 physical slot nt*16+l16 (logical d=l16*4+nt)
        short8 bfr[4];
#pragma unroll
        for (int nt = 0; nt < 4; ++nt) {
            int d = nt * 16 + l16;
            short8 qv = *(const short8*)(q2L + (jt * 64 + d) * 32 + kq);
            int4 packed;
            packed.x = pk_bf16(bf2f(qv[0]) * sf[0], bf2f(qv[1]) * sf[1]);
            packed.y = pk_bf16(bf2f(qv[2]) * sf[2], bf2f(qv[3]) * sf[3]);
            packed.z = pk_bf16(bf2f(qv[4]) * sf[4], bf2f(qv[5]) * sf[5]);
            packed.w = pk_bf16(bf2f(qv[6]) * sf[6], bf2f(qv[7]) * sf[7]);
            bfr[nt] = __builtin_bit_cast(short8, packed);
        }
        // A fragments DIRECT from global At (L2-resident, wave-coalesced)
#pragma unroll
        for (int mt = 0; mt < 4; ++mt) {
            short8 af = *(const short8*)(At + ((size_t)jt * F + it * 64 + mt * 16 + l16) * 32 + kq);
#pragma unroll
            for (int nt = 0; nt < 4; ++nt)
                acc[mt][nt] = __builtin_amdgcn_mfma_f32_16x16x32_bf16(
                    af, bfr[nt], acc[mt][nt], 0, 0, 0);
        }
    }

    // ---- epilogue: gL row scale + float4 stores (cols l16*4 .. l16*4+3) ----
    const float4* g4 = (const float4*)(gL + wc * F + it * 64);
#pragma unroll
    for (int mt = 0; mt < 4; ++mt) {
        float4 gg = g4[mt * 4 + lq];   // rows it*64 + mt*16 + lq*4 .. +3
        float* obase = out + ((size_t)(b * F + it * 64 + mt * 16 + lq * 4)) * D + l16 * 4;
        float4 v0 = {gg.x * acc[mt][0][0], gg.x * acc[mt][1][0],
                     gg.x * acc[mt][2][0], gg.x * acc[mt][3][0]};
        float4 v1 = {gg.y * acc[mt][0][1], gg.y * acc[mt][1][1],
                     gg.y * acc[mt][2][1], gg.y * acc[mt][3][1]};
        float4 v2 = {gg.z * acc[mt][0][2], gg.z * acc[mt][1][2],
                     gg.z * acc[mt][2][2], gg.z * acc[mt][3][2]};
        float4 v3 = {gg.w * acc[mt][0][3], gg.w * acc[mt][1][3],
                     gg.w * acc[mt][2][3], gg.w * acc[mt][3][3]};
        *(float4*)(obase + 0 * D) = v0;
        *(float4*)(obase + 1 * D) = v1;
        *(float4*)(obase + 2 * D) = v2;
        *(float4*)(obase + 3 * D) = v3;
    }
}

extern "C" void kernel_launch(void* const* d_in, const int* in_sizes, int n_in,
                              void* d_out, int out_size, void* d_ws, size_t ws_size,
                              hipStream_t stream) {
    const float* feature   = (const float*)d_in[0];
    const float* indicator = (const float*)d_in[1];
    const float* W_qk      = (const float*)d_in[2];
    const float* W_qkv     = (const float*)d_in[3];
    float* out = (float*)d_out;

    float* ws    = (float*)d_ws;
    float* trans = ws;                        // 2*F*D f32
    float* qkv   = trans + 2 * F * D;         // 3*F*D f32
    short* At    = (short*)(qkv + 3 * F * D); // F*F bf16 (K-tiled)
    short* q2K   = At + F * F;                // (F/32)*64*32 bf16 (K-tiled, permuted)

    hipLaunchKernelGGL(precompute_trans, dim3((5 * F * D) / 256), dim3(256), 0,
                       stream, indicator, W_qk, W_qkv, trans, qkv);
    hipLaunchKernelGGL(compute_Mt, dim3(F), dim3(256), 0, stream, trans, qkv, At, q2K);
    hipLaunchKernelGGL(fused_sg, dim3(B / 2), dim3(512), 0, stream,
                       feature, qkv, At, q2K, out);
}

// Round 11
// 144.882 us; speedup vs baseline: 1.0003x; 1.0003x over previous
//
#include <hip/hip_runtime.h>
#include <stdint.h>

#define B 1024
#define F 256
#define D 64

typedef __attribute__((ext_vector_type(8))) short short8;
typedef __attribute__((ext_vector_type(4))) float f32x4;

__device__ __forceinline__ short f2bf(float f) {
    unsigned u = __builtin_bit_cast(unsigned, f);
    u += 0x7fff + ((u >> 16) & 1);   // RNE
    return (short)(u >> 16);
}
__device__ __forceinline__ float bf2f(short s) {
    unsigned u = ((unsigned)(unsigned short)s) << 16;
    return __builtin_bit_cast(float, u);
}
// pack two f32 -> two bf16 (round-half-up), 3 VALU
__device__ __forceinline__ unsigned pk_bf16(float a, float b) {
    unsigned ua = __builtin_bit_cast(unsigned, a) + 0x8000u;
    unsigned ub = __builtin_bit_cast(unsigned, b) + 0x8000u;
    return __builtin_amdgcn_perm(ub, ua, 0x07060302u);  // [bf16(a) | bf16(b)<<16]
}

__device__ __forceinline__ float dot4(float4 a, float4 b) {
    return a.x * b.x + a.y * b.y + a.z * b.z + a.w * b.w;
}

// ---------------------------------------------------------------------------
// Workspace layout:
//   trans : 2*F*D f32
//   qkv   : 3*F*D f32
//   At    : [F/32][F][32] bf16   (gate*cross, K-tiled)      = 128 KB
//   q2K   : [F/32][64][32] bf16  (qkv2^T, K-tiled, d-PERMUTED: physical slot
//                                 p=(d&3)*16+(d>>2) so fragment nt at lane l16
//                                 holds logical col l16*4+nt -> float4 stores)
// s is computed in-LDS by fused_sg (no global round-trip).
// ---------------------------------------------------------------------------

// Kernel A: trans/qkv = indicator @ W
__global__ void precompute_trans(const float* __restrict__ indicator,
                                 const float* __restrict__ W_qk,
                                 const float* __restrict__ W_qkv,
                                 float* __restrict__ trans,
                                 float* __restrict__ qkv) {
    int idx = blockIdx.x * blockDim.x + threadIdx.x;   // 0 .. 5*F*D
    int n   = idx / (F * D);
    int rem = idx - n * (F * D);
    int f   = rem / D;
    int e   = rem - f * D;
    const float* W = (n < 2) ? (W_qk + n * D * D) : (W_qkv + (n - 2) * D * D);
    const float* ind = indicator + f * D;
    float acc = 0.f;
#pragma unroll 8
    for (int d = 0; d < D; ++d) acc += ind[d] * W[d * D + e];
    if (n < 2) trans[n * F * D + f * D + e] = acc;
    else       qkv[(n - 2) * F * D + f * D + e] = acc;
}

// Kernel B (round-5 proven): At[(j>>5)][i][j&31] = gate(i,j) ? qkv1[i].qkv0[j] : 0
//   q2K[(i>>5)][p(j)][i&31] = qkv2[i][j], p(j)=(j&3)*16+(j>>2)
__global__ __launch_bounds__(256) void compute_Mt(const float* __restrict__ trans,
                                                  const float* __restrict__ qkv,
                                                  short* __restrict__ At,
                                                  short* __restrict__ q2K) {
    int j = blockIdx.x;    // F columns
    int i = threadIdx.x;   // F threads
    const float4* t0 = (const float4*)(trans + i * D);
    const float4* t1 = (const float4*)(trans + F * D + j * D);
    const float4* q1 = (const float4*)(qkv + F * D + i * D);
    const float4* q0 = (const float4*)(qkv + j * D);
    float d0 = 0.f, d1 = 0.f;
#pragma unroll
    for (int k = 0; k < D / 4; ++k) {
        float4 a = t0[k], b = t1[k], c = q1[k], e = q0[k];
        d0 += dot4(a, b);
        d1 += dot4(c, e);
    }
    float v = (d0 > 0.f) ? d1 : 0.f;
    At[((j >> 5) * F + i) * 32 + (j & 31)] = f2bf(v);
    if (j < D) {
        int p = (j & 3) * 16 + (j >> 2);   // d-permutation for float4 stores
        q2K[((i >> 5) * D + p) * 32 + (i & 31)] = f2bf(qkv[2 * F * D + i * D + j]);
    }
}

// FUSED kernel: one block = 2 batches, 512 threads / 8 waves, 2 blocks/CU.
// Phase 1 (MLP-FIXED): each thread issues ALL 16 feature loads (8 p-iters x
//   2 batches, 256 B/thread -> 16 KB/wave in flight) BEFORE any consume.
//   R5-R10 evidence: the s-stream was never BW-bound, it was in-flight-bytes
//   bound (need ~9.4 KB/CU = 10.4 B/cyc x 900 cyc HBM latency; the per-iter
//   load-then-drain structure held only ~1.3 KB/CU -> 3x over the HBM floor,
//   insensitive to occupancy/reduce-width/access-pattern). HBM latency is now
//   paid once per wave; qkv loads (L2, ~200cy) stay per-iter under shuffles.
// Phase 2: wave w -> batch (w&1), i-tile (w>>1)*64. acc[4][4]. A from At in
//   L2 (wave-coalesced 1KB lines), B from q2K LDS-staged, scaled by s1.
__global__ __launch_bounds__(512, 4) void fused_sg(const float* __restrict__ feature,
                                                   const float* __restrict__ qkv,
                                                   const short* __restrict__ At,
                                                   const short* __restrict__ q2K,
                                                   float* __restrict__ out) {
    int bp  = blockIdx.x;
    int b0  = bp * 2;
    int tid = threadIdx.x;

    __shared__ __align__(16) short q2L[8 * 64 * 32];   // 32 KB
    __shared__ __align__(16) short s1L[2 * F];         // 1 KB
    __shared__ __align__(16) float gL[2 * F];          // 2 KB

    // ---- phase 0: stage q2K into LDS ----
    {
        const float4* Qg = (const float4*)q2K;
        float4* Ql = (float4*)q2L;
#pragma unroll
        for (int v = tid; v < 2048; v += 512) Ql[v] = Qg[v];
    }

    // ---- phase 1: s for 2 batches; 16 lanes/row, 32 rows in flight ----
    {
        int rg = tid >> 4;    // 0..31
        int l  = tid & 15;
        const float4* F0 = (const float4*)(feature + (size_t)(b0 * F) * D);
        const float4* F1 = (const float4*)(feature + (size_t)((b0 + 1) * F) * D);

        // Batch-issue all 16 feature loads (statically indexed arrays -> regs)
        float4 fv0[8], fv1[8];
#pragma unroll
        for (int p = 0; p < 8; ++p) {
            int f = p * 32 + rg;
            fv0[p] = F0[f * 16 + l];
            fv1[p] = F1[f * 16 + l];
        }

#pragma unroll
        for (int p = 0; p < 8; ++p) {
            int f = p * 32 + rg;
            float4 q0 = ((const float4*)(qkv + f * D))[l];
            float4 q1 = ((const float4*)(qkv + F * D + f * D))[l];
            float4 q2 = ((const float4*)(qkv + 2 * F * D + f * D))[l];
            float a00 = dot4(fv0[p], q0);
            float a01 = dot4(fv0[p], q1);
            float a02 = dot4(fv0[p], q2);
            float a10 = dot4(fv1[p], q0);
            float a11 = dot4(fv1[p], q1);
            float a12 = dot4(fv1[p], q2);
#pragma unroll
            for (int m = 1; m < 16; m <<= 1) {
                a00 += __shfl_xor(a00, m, 64);
                a01 += __shfl_xor(a01, m, 64);
                a02 += __shfl_xor(a02, m, 64);
                a10 += __shfl_xor(a10, m, 64);
                a11 += __shfl_xor(a11, m, 64);
                a12 += __shfl_xor(a12, m, 64);
            }
            if (l == 0) {
                gL[f]      = a00 * a02;
                gL[F + f]  = a10 * a12;
                s1L[f]     = f2bf(a01);
                s1L[F + f] = f2bf(a11);
            }
        }
    }
    __syncthreads();

    // ---- phase 2: MFMA GEMM, A from global (L2), B from LDS ----
    int w    = tid >> 6;
    int lane = tid & 63;
    int l16  = lane & 15;
    int lq   = lane >> 4;
    int kq   = lq * 8;
    int wc   = w & 1;        // batch within pair
    int it   = w >> 1;       // i-tile: rows [it*64, it*64+64)
    int b    = b0 + wc;

    f32x4 acc[4][4];
#pragma unroll
    for (int mt = 0; mt < 4; ++mt)
#pragma unroll
        for (int nt = 0; nt < 4; ++nt) acc[mt][nt] = (f32x4){0.f, 0.f, 0.f, 0.f};

    for (int jt = 0; jt < F / 32; ++jt) {
        // s1 fragment from LDS (broadcast within 16-lane groups)
        short8 sv = *(const short8*)(s1L + wc * F + jt * 32 + kq);
        float sf[8];
#pragma unroll
        for (int e = 0; e < 8; ++e) sf[e] = bf2f(sv[e]);

        // B fragments from LDS: q2 physical slot nt*16+l16 (logical d=l16*4+nt)
        short8 bfr[4];
#pragma unroll
        for (int nt = 0; nt < 4; ++nt) {
            int d = nt * 16 + l16;
            short8 qv = *(const short8*)(q2L + (jt * 64 + d) * 32 + kq);
            int4 packed;
            packed.x = pk_bf16(bf2f(qv[0]) * sf[0], bf2f(qv[1]) * sf[1]);
            packed.y = pk_bf16(bf2f(qv[2]) * sf[2], bf2f(qv[3]) * sf[3]);
            packed.z = pk_bf16(bf2f(qv[4]) * sf[4], bf2f(qv[5]) * sf[5]);
            packed.w = pk_bf16(bf2f(qv[6]) * sf[6], bf2f(qv[7]) * sf[7]);
            bfr[nt] = __builtin_bit_cast(short8, packed);
        }
        // A fragments DIRECT from global At (L2-resident, wave-coalesced)
#pragma unroll
        for (int mt = 0; mt < 4; ++mt) {
            short8 af = *(const short8*)(At + ((size_t)jt * F + it * 64 + mt * 16 + l16) * 32 + kq);
#pragma unroll
            for (int nt = 0; nt < 4; ++nt)
                acc[mt][nt] = __builtin_amdgcn_mfma_f32_16x16x32_bf16(
                    af, bfr[nt], acc[mt][nt], 0, 0, 0);
        }
    }

    // ---- epilogue: gL row scale + float4 stores (cols l16*4 .. l16*4+3) ----
    const float4* g4 = (const float4*)(gL + wc * F + it * 64);
#pragma unroll
    for (int mt = 0; mt < 4; ++mt) {
        float4 gg = g4[mt * 4 + lq];   // rows it*64 + mt*16 + lq*4 .. +3
        float* obase = out + ((size_t)(b * F + it * 64 + mt * 16 + lq * 4)) * D + l16 * 4;
        float4 v0 = {gg.x * acc[mt][0][0], gg.x * acc[mt][1][0],
                     gg.x * acc[mt][2][0], gg.x * acc[mt][3][0]};
        float4 v1 = {gg.y * acc[mt][0][1], gg.y * acc[mt][1][1],
                     gg.y * acc[mt][2][1], gg.y * acc[mt][3][1]};
        float4 v2 = {gg.z * acc[mt][0][2], gg.z * acc[mt][1][2],
                     gg.z * acc[mt][2][2], gg.z * acc[mt][3][2]};
        float4 v3 = {gg.w * acc[mt][0][3], gg.w * acc[mt][1][3],
                     gg.w * acc[mt][2][3], gg.w * acc[mt][3][3]};
        *(float4*)(obase + 0 * D) = v0;
        *(float4*)(obase + 1 * D) = v1;
        *(float4*)(obase + 2 * D) = v2;
        *(float4*)(obase + 3 * D) = v3;
    }
}

extern "C" void kernel_launch(void* const* d_in, const int* in_sizes, int n_in,
                              void* d_out, int out_size, void* d_ws, size_t ws_size,
                              hipStream_t stream) {
    const float* feature   = (const float*)d_in[0];
    const float* indicator = (const float*)d_in[1];
    const float* W_qk      = (const float*)d_in[2];
    const float* W_qkv     = (const float*)d_in[3];
    float* out = (float*)d_out;

    float* ws    = (float*)d_ws;
    float* trans = ws;                        // 2*F*D f32
    float* qkv   = trans + 2 * F * D;         // 3*F*D f32
    short* At    = (short*)(qkv + 3 * F * D); // F*F bf16 (K-tiled)
    short* q2K   = At + F * F;                // (F/32)*64*32 bf16 (K-tiled, permuted)

    hipLaunchKernelGGL(precompute_trans, dim3((5 * F * D) / 256), dim3(256), 0,
                       stream, indicator, W_qk, W_qkv, trans, qkv);
    hipLaunchKernelGGL(compute_Mt, dim3(F), dim3(256), 0, stream, trans, qkv, At, q2K);
    hipLaunchKernelGGL(fused_sg, dim3(B / 2), dim3(512), 0, stream,
                       feature, qkv, At, q2K, out);
}

// Round 12
// 140.815 us; speedup vs baseline: 1.0292x; 1.0289x over previous
//
#include <hip/hip_runtime.h>
#include <stdint.h>

#define B 1024
#define F 256
#define D 64

typedef __attribute__((ext_vector_type(8))) short short8;
typedef __attribute__((ext_vector_type(4))) float f32x4;

__device__ __forceinline__ short f2bf(float f) {
    unsigned u = __builtin_bit_cast(unsigned, f);
    u += 0x7fff + ((u >> 16) & 1);   // RNE
    return (short)(u >> 16);
}
__device__ __forceinline__ float bf2f(short s) {
    unsigned u = ((unsigned)(unsigned short)s) << 16;
    return __builtin_bit_cast(float, u);
}
// pack two f32 -> two bf16 (round-half-up), 3 VALU
__device__ __forceinline__ unsigned pk_bf16(float a, float b) {
    unsigned ua = __builtin_bit_cast(unsigned, a) + 0x8000u;
    unsigned ub = __builtin_bit_cast(unsigned, b) + 0x8000u;
    return __builtin_amdgcn_perm(ub, ua, 0x07060302u);  // [bf16(a) | bf16(b)<<16]
}

__device__ __forceinline__ float dot4(float4 a, float4 b) {
    return a.x * b.x + a.y * b.y + a.z * b.z + a.w * b.w;
}

// fire-and-forget 16B global->LDS (per-lane global addr, wave-uniform LDS base
// + lane*16 — our tid-linear mapping satisfies this)
__device__ __forceinline__ void gload_lds16(const float* g, float* l) {
    __builtin_amdgcn_global_load_lds(
        (const __attribute__((address_space(1))) unsigned int*)g,
        (__attribute__((address_space(3))) unsigned int*)l, 16, 0, 0);
}

// ---------------------------------------------------------------------------
// Workspace:
//   trans : 2*F*D f32
//   qkv   : 3*F*D f32
//   At    : [F/32][F][32] bf16   (gate*cross, K-tiled)      = 128 KB
//   q2K   : [F/32][64][32] bf16  (qkv2^T, K-tiled, d-permuted p=(d&3)*16+(d>>2))
// ---------------------------------------------------------------------------

__global__ void precompute_trans(const float* __restrict__ indicator,
                                 const float* __restrict__ W_qk,
                                 const float* __restrict__ W_qkv,
                                 float* __restrict__ trans,
                                 float* __restrict__ qkv) {
    int idx = blockIdx.x * blockDim.x + threadIdx.x;   // 0 .. 5*F*D
    int n   = idx / (F * D);
    int rem = idx - n * (F * D);
    int f   = rem / D;
    int e   = rem - f * D;
    const float* W = (n < 2) ? (W_qk + n * D * D) : (W_qkv + (n - 2) * D * D);
    const float* ind = indicator + f * D;
    float acc = 0.f;
#pragma unroll 8
    for (int d = 0; d < D; ++d) acc += ind[d] * W[d * D + e];
    if (n < 2) trans[n * F * D + f * D + e] = acc;
    else       qkv[(n - 2) * F * D + f * D + e] = acc;
}

__global__ __launch_bounds__(256) void compute_Mt(const float* __restrict__ trans,
                                                  const float* __restrict__ qkv,
                                                  short* __restrict__ At,
                                                  short* __restrict__ q2K) {
    int j = blockIdx.x;    // F columns
    int i = threadIdx.x;   // F threads
    const float4* t0 = (const float4*)(trans + i * D);
    const float4* t1 = (const float4*)(trans + F * D + j * D);
    const float4* q1 = (const float4*)(qkv + F * D + i * D);
    const float4* q0 = (const float4*)(qkv + j * D);
    float d0 = 0.f, d1 = 0.f;
#pragma unroll
    for (int k = 0; k < D / 4; ++k) {
        float4 a = t0[k], b = t1[k], c = q1[k], e = q0[k];
        d0 += dot4(a, b);
        d1 += dot4(c, e);
    }
    float v = (d0 > 0.f) ? d1 : 0.f;
    At[((j >> 5) * F + i) * 32 + (j & 31)] = f2bf(v);
    if (j < D) {
        int p = (j & 3) * 16 + (j >> 2);
        q2K[((i >> 5) * D + p) * 32 + (i & 31)] = f2bf(qkv[2 * F * D + i * D + j]);
    }
}

// FUSED kernel: one block = 2 batches, 512 threads / 8 waves, 2 blocks/CU.
// Phase 1 (gload_lds pipeline): feature flows HBM->LDS via fire-and-forget
//   global_load_lds width-16, 16KB chunks (64 rows, one batch each), double-
//   buffered: stage(c+1) issued BEFORE computing chunk c; the __syncthreads
//   drain at chunk end lands c+1's staging under c's compute. Removes the
//   consumed-load dependency that held the R5-R11 s-stream at ~2.4 TB/s
//   (harness fill at 6.5 TB/s = the no-consumer ceiling).
// Phase 2: unchanged (wave w -> batch w&1, i-tile w>>1; A direct from At in
//   L2 wave-coalesced; B = s1-scaled q2 from LDS; float4 stores).
__global__ __launch_bounds__(512, 2) void fused_sg(const float* __restrict__ feature,
                                                   const float* __restrict__ qkv,
                                                   const short* __restrict__ At,
                                                   const short* __restrict__ q2K,
                                                   float* __restrict__ out) {
    int bp  = blockIdx.x;
    int b0  = bp * 2;
    int tid = threadIdx.x;

    __shared__ __align__(16) short q2L[8 * 64 * 32];   // 32 KB
    __shared__ __align__(16) float fbuf[2][4096];      // 2 x 16 KB feature chunks
    __shared__ __align__(16) short s1L[2 * F];         // 1 KB
    __shared__ __align__(16) float gL[2 * F];          // 2 KB

    // ---- stage q2K into LDS (regular loads, overlaps with chunk-0 staging) ----
    {
        const float4* Qg = (const float4*)q2K;
        float4* Ql = (float4*)q2L;
#pragma unroll
        for (int v = tid; v < 2048; v += 512) Ql[v] = Qg[v];
    }

    // ---- phase 1: s via chunked gload_lds pipeline ----
    {
        int rg = tid >> 4;    // 0..31 (row group)
        int l  = tid & 15;    // lane-in-row

        // chunk c in [0,8): batch c>>2, rows [(c&3)*64, +64)
        // stage: 512 threads x 2 x 16B = 16 KB, tid-linear (wave-uniform+lane*16)
#define STAGE(c, buf)                                                          \
        {                                                                      \
            const float* gb = feature +                                        \
                ((size_t)((b0 + ((c) >> 2)) * F + (((c) & 3) * 64)) * D);      \
            float* lb = fbuf[buf];                                             \
            gload_lds16(gb + tid * 4, lb + tid * 4);                           \
            gload_lds16(gb + 2048 + tid * 4, lb + 2048 + tid * 4);             \
        }

        STAGE(0, 0)
        __syncthreads();
        for (int c = 0; c < 8; ++c) {
            int buf = c & 1;
            if (c < 7) STAGE(c + 1, buf ^ 1)
            int bsel  = c >> 2;
            int fbase = (c & 3) * 64;
            const float4* fb = (const float4*)fbuf[buf];
#pragma unroll
            for (int q = 0; q < 2; ++q) {
                int r = q * 32 + rg;
                int f = fbase + r;
                float4 fv = fb[r * 16 + l];
                float4 q0 = ((const float4*)(qkv + f * D))[l];
                float4 q1 = ((const float4*)(qkv + F * D + f * D))[l];
                float4 q2 = ((const float4*)(qkv + 2 * F * D + f * D))[l];
                float a0 = dot4(fv, q0);
                float a1 = dot4(fv, q1);
                float a2 = dot4(fv, q2);
#pragma unroll
                for (int m = 1; m < 16; m <<= 1) {
                    a0 += __shfl_xor(a0, m, 64);
                    a1 += __shfl_xor(a1, m, 64);
                    a2 += __shfl_xor(a2, m, 64);
                }
                if (l == 0) {
                    gL[bsel * F + f]  = a0 * a2;
                    s1L[bsel * F + f] = f2bf(a1);
                }
            }
            __syncthreads();   // drains stage(c+1) under compute; buffers swap safely
        }
#undef STAGE
    }

    // ---- phase 2: MFMA GEMM, A from global (L2), B from LDS ----
    int w    = tid >> 6;
    int lane = tid & 63;
    int l16  = lane & 15;
    int lq   = lane >> 4;
    int kq   = lq * 8;
    int wc   = w & 1;        // batch within pair
    int it   = w >> 1;       // i-tile: rows [it*64, it*64+64)
    int b    = b0 + wc;

    f32x4 acc[4][4];
#pragma unroll
    for (int mt = 0; mt < 4; ++mt)
#pragma unroll
        for (int nt = 0; nt < 4; ++nt) acc[mt][nt] = (f32x4){0.f, 0.f, 0.f, 0.f};

    for (int jt = 0; jt < F / 32; ++jt) {
        short8 sv = *(const short8*)(s1L + wc * F + jt * 32 + kq);
        float sf[8];
#pragma unroll
        for (int e = 0; e < 8; ++e) sf[e] = bf2f(sv[e]);

        short8 bfr[4];
#pragma unroll
        for (int nt = 0; nt < 4; ++nt) {
            int d = nt * 16 + l16;
            short8 qv = *(const short8*)(q2L + (jt * 64 + d) * 32 + kq);
            int4 packed;
            packed.x = pk_bf16(bf2f(qv[0]) * sf[0], bf2f(qv[1]) * sf[1]);
            packed.y = pk_bf16(bf2f(qv[2]) * sf[2], bf2f(qv[3]) * sf[3]);
            packed.z = pk_bf16(bf2f(qv[4]) * sf[4], bf2f(qv[5]) * sf[5]);
            packed.w = pk_bf16(bf2f(qv[6]) * sf[6], bf2f(qv[7]) * sf[7]);
            bfr[nt] = __builtin_bit_cast(short8, packed);
        }
#pragma unroll
        for (int mt = 0; mt < 4; ++mt) {
            short8 af = *(const short8*)(At + ((size_t)jt * F + it * 64 + mt * 16 + l16) * 32 + kq);
#pragma unroll
            for (int nt = 0; nt < 4; ++nt)
                acc[mt][nt] = __builtin_amdgcn_mfma_f32_16x16x32_bf16(
                    af, bfr[nt], acc[mt][nt], 0, 0, 0);
        }
    }

    // ---- epilogue: gL row scale + float4 stores (cols l16*4 .. l16*4+3) ----
    const float4* g4 = (const float4*)(gL + wc * F + it * 64);
#pragma unroll
    for (int mt = 0; mt < 4; ++mt) {
        float4 gg = g4[mt * 4 + lq];
        float* obase = out + ((size_t)(b * F + it * 64 + mt * 16 + lq * 4)) * D + l16 * 4;
        float4 v0 = {gg.x * acc[mt][0][0], gg.x * acc[mt][1][0],
                     gg.x * acc[mt][2][0], gg.x * acc[mt][3][0]};
        float4 v1 = {gg.y * acc[mt][0][1], gg.y * acc[mt][1][1],
                     gg.y * acc[mt][2][1], gg.y * acc[mt][3][1]};
        float4 v2 = {gg.z * acc[mt][0][2], gg.z * acc[mt][1][2],
                     gg.z * acc[mt][2][2], gg.z * acc[mt][3][2]};
        float4 v3 = {gg.w * acc[mt][0][3], gg.w * acc[mt][1][3],
                     gg.w * acc[mt][2][3], gg.w * acc[mt][3][3]};
        *(float4*)(obase + 0 * D) = v0;
        *(float4*)(obase + 1 * D) = v1;
        *(float4*)(obase + 2 * D) = v2;
        *(float4*)(obase + 3 * D) = v3;
    }
}

extern "C" void kernel_launch(void* const* d_in, const int* in_sizes, int n_in,
                              void* d_out, int out_size, void* d_ws, size_t ws_size,
                              hipStream_t stream) {
    const float* feature   = (const float*)d_in[0];
    const float* indicator = (const float*)d_in[1];
    const float* W_qk      = (const float*)d_in[2];
    const float* W_qkv     = (const float*)d_in[3];
    float* out = (float*)d_out;

    float* ws    = (float*)d_ws;
    float* trans = ws;                        // 2*F*D f32
    float* qkv   = trans + 2 * F * D;         // 3*F*D f32
    short* At    = (short*)(qkv + 3 * F * D); // F*F bf16 (K-tiled)
    short* q2K   = At + F * F;                // (F/32)*64*32 bf16 (K-tiled, permuted)

    hipLaunchKernelGGL(precompute_trans, dim3((5 * F * D) / 256), dim3(256), 0,
                       stream, indicator, W_qk, W_qkv, trans, qkv);
    hipLaunchKernelGGL(compute_Mt, dim3(F), dim3(256), 0, stream, trans, qkv, At, q2K);
    hipLaunchKernelGGL(fused_sg, dim3(B / 2), dim3(512), 0, stream,
                       feature, qkv, At, q2K, out);
}